// Round 7
// baseline (1718.768 us; speedup 1.0000x reference)
//
#include <hip/hip_runtime.h>
#include <hip/hip_bf16.h>

// Problem constants
static constexpr int PN = 16384;  // paths
static constexpr int TT = 8;      // seq len
static constexpr int LN = 4096;   // links
static constexpr int KG = 16;     // path_to_link K
static constexpr int NN = 2048;   // nodes
static constexpr int K2G = 32;    // path_to_node K2
static constexpr int MG = 8;      // link_to_node M
static constexpr int ITER = 8;
static constexpr int GB = 1024;   // grid for fused iter kernels (4/CU resident)

typedef __attribute__((ext_vector_type(8))) short short8b;   // 8 bf16 (4 VGPRs)
typedef __attribute__((ext_vector_type(4))) float f32x4;

__device__ __forceinline__ float frcp(float x) {
    return __builtin_amdgcn_rcpf(x);   // v_rcp_f32, ~1ulp
}
__device__ __forceinline__ float sigmoidf_(float x) {
    return frcp(1.0f + __expf(-x));
}
__device__ __forceinline__ float tanhf_(float x) {
    return 1.0f - 2.0f * frcp(__expf(2.0f * x) + 1.0f);
}
__device__ __forceinline__ float softplusf_(float x) {
    return fmaxf(x, 0.0f) + log1pf(__expf(-fabsf(x)));
}
__device__ __forceinline__ unsigned short f2bf(float f) {
    unsigned int x = __float_as_uint(f);
    unsigned int r = (x + 0x7fffu + ((x >> 16) & 1u)) >> 16;
    return (unsigned short)r;
}
__device__ __forceinline__ float bf2f(unsigned short u) {
    return __uint_as_float(((unsigned int)u) << 16);
}

// ---------------------------------------------------------------------------
// Hand-rolled grid barrier (device-scope). 1024 blocks, 8 striped counter
// lines (128 arrivals each); last arriver of a line bumps master. Blocks that
// have no post-barrier work arrive WITHOUT polling. Slot zeroed via
// hipMemsetAsync before the graph runs. [R4 lesson: cg::sync ~70us; this ~4us]
// ---------------------------------------------------------------------------
__device__ __forceinline__ void bar_arrive(int* slot, bool wait) {
    __threadfence();          // release: all my stores visible device-wide
    __syncthreads();          // every thread of the block has fenced
    if (threadIdx.x == 0) {
        int line = blockIdx.x & 7;
        int v = atomicAdd(slot + line * 16, 1);
        if (v == (GB / 8) - 1) atomicAdd(slot + 128, 1);
        if (wait) {
            while (__hip_atomic_load(slot + 128, __ATOMIC_ACQUIRE,
                                     __HIP_MEMORY_SCOPE_AGENT) < 8)
                __builtin_amdgcn_s_sleep(2);
        }
    }
    if (wait) {
        __syncthreads();
        __threadfence();      // acquire side for all threads
    }
}

// ---------------------------------------------------------------------------
// K_setup: heterogeneous launch.
//   blocks [0,1024)    : path encoder, 16 rows/block, w2 in LDS
//   blocks [1024,1280) : link encoder, 16 rows/block, w2 in LDS
//   blocks [1280,1568) : 6x GRU weight transpose fp32[64][192]->bf16[192][64]
// ---------------------------------------------------------------------------
__global__ __launch_bounds__(256) void k_setup(
    const float* __restrict__ ft, const float* __restrict__ fpk,
    const float* __restrict__ fps, const float* __restrict__ cap,
    const int* __restrict__ ptl, const int* __restrict__ ldt,
    const float* __restrict__ pe_w1, const float* __restrict__ pe_b1,
    const float* __restrict__ pe_w2, const float* __restrict__ pe_b2,
    const float* __restrict__ le_w1, const float* __restrict__ le_b1,
    const float* __restrict__ le_w2, const float* __restrict__ le_b2,
    const float* __restrict__ pgru_wx, const float* __restrict__ pgru_wh,
    const float* __restrict__ lgru_wx, const float* __restrict__ lgru_wh,
    const float* __restrict__ dgru_wx, const float* __restrict__ dgru_wh,
    unsigned short* __restrict__ pwxT, unsigned short* __restrict__ pwhT,
    unsigned short* __restrict__ lwxT, unsigned short* __restrict__ lwhT,
    unsigned short* __restrict__ dwxT, unsigned short* __restrict__ dwhT,
    float* __restrict__ path_state, float* __restrict__ link_state)
{
    int b = blockIdx.x;
    int tid = threadIdx.x;
    if (b >= 1280) {
        const float* srcs[6] = {pgru_wx, pgru_wh, lgru_wx, lgru_wh, dgru_wx, dgru_wh};
        unsigned short* dsts[6] = {pwxT, pwhT, lwxT, lwhT, dwxT, dwhT};
        int i = (b - 1280) * 256 + tid;     // 0 .. 6*12288-1
        int mi = i / 12288, o = i - mi * 12288;
        int n = o >> 6, k = o & 63;
        dsts[mi][o] = f2bf(srcs[mi][k * 192 + n]);
        return;
    }
    __shared__ __align__(16) float w2s[4096];
    __shared__ float w1s[192], b1s[64], b2s[64];
    __shared__ float h1s[4][64];
    bool isPath = (b < 1024);
    const float* w1p = isPath ? pe_w1 : le_w1;
    const float* b1p = isPath ? pe_b1 : le_b1;
    const float* w2p = isPath ? pe_w2 : le_w2;
    const float* b2p = isPath ? pe_b2 : le_b2;
    for (int i = tid; i < 4096; i += 256) w2s[i] = w2p[i];
    if (tid < 192) w1s[tid] = w1p[tid];
    if (tid < 64) { b1s[tid] = b1p[tid]; b2s[tid] = b2p[tid]; }
    __syncthreads();
    int rl = tid >> 6, d = tid & 63;
    int base = (isPath ? b : (b - 1024)) * 16;
    for (int rp = 0; rp < 4; ++rp) {
        int row = base + rp * 4 + rl;
        float h;
        if (isPath) {
            float x0 = ft[row]  * 1e-4f;
            float x1 = fpk[row] * 1e-3f;
            float x2 = fps[row] * 1e-3f;
            h = b1s[d] + x0 * w1s[d] + x1 * w1s[64 + d] + x2 * w1s[128 + d];
        } else {
            float v = 0.0f;
            if (d < 16) v = ft[ptl[(row * 16 + d) * 2]];
            v += __shfl_down(v, 8);
            v += __shfl_down(v, 4);
            v += __shfl_down(v, 2);
            v += __shfl_down(v, 1);
            float ssum = __shfl(v, 0);
            float cv = cap[row];
            float load = ssum * frcp(cv * 1e9f);
            float x2 = (ldt[row] == 0) ? 1.0f : 0.0f;
            h = b1s[d] + cv * 0.01f * w1s[d] + load * w1s[64 + d] + x2 * w1s[128 + d];
        }
        h1s[rl][d] = fmaxf(h, 0.0f);
        __syncthreads();
        float acc = b2s[d];
#pragma unroll 8
        for (int k = 0; k < 64; ++k) acc += h1s[rl][k] * w2s[k * 64 + d];
        float* dst = isPath ? path_state : link_state;
        dst[(size_t)row * 64 + d] = fmaxf(acc, 0.0f);
        __syncthreads();
    }
}

// ---------------------------------------------------------------------------
// K3: device encoder, w2 staged in LDS
// ---------------------------------------------------------------------------
__global__ __launch_bounds__(256) void k_device_encode(
    const float* __restrict__ link_state, const int* __restrict__ ltn,
    const int* __restrict__ nodes,
    const float* __restrict__ w1, const float* __restrict__ b1,
    const float* __restrict__ w2, const float* __restrict__ b2,
    float* __restrict__ device_state)
{
    __shared__ __align__(16) float w2s[4096];
    __shared__ float h1s[4][64];
    int tid = threadIdx.x;
    for (int i = tid; i < 4096; i += 256) w2s[i] = w2[i];
    int rl = tid >> 6, d = tid & 63;
    int row = blockIdx.x * 4 + rl;
    float s = 0.0f;
#pragma unroll
    for (int m = 0; m < MG; ++m)
        s += link_state[(size_t)ltn[row * MG + m] * 64 + d];
#pragma unroll
    for (int o = 32; o > 0; o >>= 1) s += __shfl_xor(s, o);
    float dlm = s * (1.0f / 64.0f);
    float enc = (nodes[row] == 0) ? 1.0f : 0.0f;
    float h = b1[d] + enc * w1[d] + dlm * w1[64 + d];
    h1s[rl][d] = fmaxf(h, 0.0f);
    __syncthreads();
    float acc = b2[d];
#pragma unroll 8
    for (int k = 0; k < 64; ++k) acc += h1s[rl][k] * w2s[k * 64 + d];
    device_state[(size_t)row * 64 + d] = fmaxf(acc, 0.0f);
}

// ---------------------------------------------------------------------------
// Edge (link/device) GRU core; shared arrays passed in (hoisted to avoid
// double allocation for the two template instantiations).
// ---------------------------------------------------------------------------
template <int Kg>
__device__ __forceinline__ void edge_body(
    int* idxs, unsigned short (*Ab)[72], unsigned short (*Hbs)[72],
    float (*Hf)[68],
    const unsigned short* __restrict__ wxT, const unsigned short* __restrict__ whT,
    const float* __restrict__ bx, const float* __restrict__ bh,
    const int* __restrict__ p2e, const unsigned short* __restrict__ pssb,
    float* __restrict__ state, int blk)
{
    int tid = threadIdx.x;
    int r0 = blk * 16;
    for (int i = tid; i < 16 * Kg * 2; i += 256)
        idxs[i] = p2e[(size_t)r0 * Kg * 2 + i];
    __syncthreads();
    {
        int r = tid >> 4, c4 = (tid & 15) * 4;
        int row = r0 + r;
        float4 s = {0.f, 0.f, 0.f, 0.f};
#pragma unroll
        for (int k = 0; k < Kg; ++k) {
            int pi = idxs[(r * Kg + k) * 2];
            int ti = idxs[(r * Kg + k) * 2 + 1];
            ushort4 v = *(const ushort4*)(pssb + ((size_t)pi * TT + ti - 1) * 64 + c4);
            s.x += bf2f(v.x); s.y += bf2f(v.y);
            s.z += bf2f(v.z); s.w += bf2f(v.w);
        }
        ushort4 ua;
        ua.x = f2bf(s.x); ua.y = f2bf(s.y); ua.z = f2bf(s.z); ua.w = f2bf(s.w);
        *(ushort4*)&Ab[r][c4] = ua;
        float4 hv = *(const float4*)(state + (size_t)row * 64 + c4);
        *(float4*)&Hf[r][c4] = hv;
        ushort4 uh;
        uh.x = f2bf(hv.x); uh.y = f2bf(hv.y); uh.z = f2bf(hv.z); uh.w = f2bf(hv.w);
        *(ushort4*)&Hbs[r][c4] = uh;
    }
    __syncthreads();
    int lane = tid & 63, w = tid >> 6;
    int c = lane & 15, q = lane >> 4;
    int d = 16 * w + c;
    short8b fx[3][2], fh[3][2];
#pragma unroll
    for (int g = 0; g < 3; ++g)
#pragma unroll
        for (int kt = 0; kt < 2; ++kt) {
            int off = (g * 64 + 16 * w + c) * 64 + kt * 32 + q * 8;
            fx[g][kt] = *(const short8b*)(wxT + off);
            fh[g][kt] = *(const short8b*)(whT + off);
        }
    f32x4 ax[3], ah[3];
#pragma unroll
    for (int g = 0; g < 3; ++g) {
        ax[g] = (f32x4){0.f, 0.f, 0.f, 0.f};
        ah[g] = (f32x4){0.f, 0.f, 0.f, 0.f};
    }
#pragma unroll
    for (int kt = 0; kt < 2; ++kt) {
        short8b aA = *(const short8b*)&Ab[c][kt * 32 + q * 8];
        short8b aH = *(const short8b*)&Hbs[c][kt * 32 + q * 8];
#pragma unroll
        for (int g = 0; g < 3; ++g) {
            ax[g] = __builtin_amdgcn_mfma_f32_16x16x32_bf16(aA, fx[g][kt], ax[g], 0, 0, 0);
            ah[g] = __builtin_amdgcn_mfma_f32_16x16x32_bf16(aH, fh[g][kt], ah[g], 0, 0, 0);
        }
    }
    float bz = bx[d] + bh[d];
    float br = bx[64 + d] + bh[64 + d];
    float bxc = bx[128 + d];
    float bhc = bh[128 + d];
#pragma unroll
    for (int r = 0; r < 4; ++r) {
        int m = q * 4 + r;
        float z  = sigmoidf_(ax[0][r] + ah[0][r] + bz);
        float rr = sigmoidf_(ax[1][r] + ah[1][r] + br);
        float cc = tanhf_(ax[2][r] + bxc + rr * (ah[2][r] + bhc));
        float hn = z * Hf[m][d] + (1.0f - z) * cc;
        state[(size_t)(r0 + m) * 64 + d] = hn;
    }
}

// ---------------------------------------------------------------------------
// K_iter: one full message-passing iteration in ONE launch.
//   all 1024 blocks : pscan (x-gather + xproj + 8-step GRU, MFMA)
//   grid barrier (hand-rolled; blocks >=384 arrive & exit)
//   blocks [0,256)  : link GRU update;  [256,384): device GRU update
// LDS 36.1KB -> 4 blocks/CU; VGPR capped 128 -> all 1024 blocks co-resident.
// ---------------------------------------------------------------------------
__global__ __launch_bounds__(256, 4) void k_iter(
    const float* __restrict__ ls, const float* __restrict__ dst,
    const int* __restrict__ ltp, const int* __restrict__ ntp,
    const unsigned short* __restrict__ wxT, const unsigned short* __restrict__ whT,
    const float* __restrict__ bx, const float* __restrict__ bh,
    float* __restrict__ path_state, unsigned short* __restrict__ pssb,
    const unsigned short* __restrict__ lwxT, const unsigned short* __restrict__ lwhT,
    const float* __restrict__ lbx, const float* __restrict__ lbh,
    const int* __restrict__ ptl,
    const unsigned short* __restrict__ dwxT, const unsigned short* __restrict__ dwhT,
    const float* __restrict__ dbx, const float* __restrict__ dbh,
    const int* __restrict__ ptn,
    float* __restrict__ link_state, float* __restrict__ device_state,
    int* __restrict__ barslot)
{
    __shared__ __align__(16) unsigned short Xs[8][16][72];
    __shared__ __align__(16) unsigned short Hb[2][16][72];
    // edge-phase arrays (hoisted; sized for Kg=32)
    __shared__ int e_idxs[16 * K2G * 2];
    __shared__ __align__(16) unsigned short e_Ab[16][72];
    __shared__ __align__(16) unsigned short e_Hbs[16][72];
    __shared__ __align__(16) float e_Hf[16][68];

    int tid = threadIdx.x;
    int p0 = blockIdx.x * 16;

    // ---- pscan phase ----
    {
        int r = tid >> 4, c0 = (tid & 15) * 4;
        float4 a = *(const float4*)(path_state + (size_t)(p0 + r) * 64 + c0);
        ushort4 u;
        u.x = f2bf(a.x); u.y = f2bf(a.y); u.z = f2bf(a.z); u.w = f2bf(a.w);
        *(ushort4*)&Hb[0][r][c0] = u;
    }
    {
        int t = tid >> 5, m = (tid >> 1) & 15, half = tid & 1;
        int gi = (p0 + m) * TT + t;
        int il = ltp[gi], in = ntp[gi];
        const float4* l4 = (const float4*)(ls + (size_t)il * 64 + half * 32);
        const float4* n4 = (const float4*)(dst + (size_t)in * 64 + half * 32);
#pragma unroll
        for (int j = 0; j < 8; ++j) {
            float4 a = l4[j], b = n4[j];
            ushort4 u;
            u.x = f2bf(a.x + b.x); u.y = f2bf(a.y + b.y);
            u.z = f2bf(a.z + b.z); u.w = f2bf(a.w + b.w);
            *(ushort4*)&Xs[t][m][half * 32 + j * 4] = u;
        }
    }
    int lane = tid & 63, w = tid >> 6;
    int c = lane & 15, q = lane >> 4;
    int d = 16 * w + c;
    short8b fx[3][2], fh[3][2];
#pragma unroll
    for (int g = 0; g < 3; ++g)
#pragma unroll
        for (int kt = 0; kt < 2; ++kt) {
            int off = (g * 64 + 16 * w + c) * 64 + kt * 32 + q * 8;
            fx[g][kt] = *(const short8b*)(wxT + off);
            fh[g][kt] = *(const short8b*)(whT + off);
        }
    float bz = bx[d] + bh[d];
    float br = bx[64 + d] + bh[64 + d];
    float bxc = bx[128 + d];
    float bhc = bh[128 + d];
    float hold[4];
#pragma unroll
    for (int r_ = 0; r_ < 4; ++r_)
        hold[r_] = path_state[(size_t)(p0 + q * 4 + r_) * 64 + d];
    __syncthreads();

    for (int t = 0; t < TT; ++t) {
        int rb = t & 1, wb = rb ^ 1;
        f32x4 ax[3], ah[3];
#pragma unroll
        for (int g = 0; g < 3; ++g) {
            ax[g] = (f32x4){0.f, 0.f, 0.f, 0.f};
            ah[g] = (f32x4){0.f, 0.f, 0.f, 0.f};
        }
#pragma unroll
        for (int kt = 0; kt < 2; ++kt) {
            short8b aX = *(const short8b*)&Xs[t][c][kt * 32 + q * 8];
            short8b aH = *(const short8b*)&Hb[rb][c][kt * 32 + q * 8];
#pragma unroll
            for (int g = 0; g < 3; ++g) {
                ax[g] = __builtin_amdgcn_mfma_f32_16x16x32_bf16(aX, fx[g][kt], ax[g], 0, 0, 0);
                ah[g] = __builtin_amdgcn_mfma_f32_16x16x32_bf16(aH, fh[g][kt], ah[g], 0, 0, 0);
            }
        }
#pragma unroll
        for (int r_ = 0; r_ < 4; ++r_) {
            float z  = sigmoidf_(ax[0][r_] + ah[0][r_] + bz);
            float rr = sigmoidf_(ax[1][r_] + ah[1][r_] + br);
            float cc = tanhf_(ax[2][r_] + bxc + rr * (ah[2][r_] + bhc));
            float hn = z * hold[r_] + (1.0f - z) * cc;
            hold[r_] = hn;
            Hb[wb][q * 4 + r_][d] = f2bf(hn);
        }
        __syncthreads();
        {
            int r = tid >> 4, c0 = (tid & 15) * 4;
            ushort4 v = *(const ushort4*)&Hb[wb][r][c0];
            *(ushort4*)(pssb + ((size_t)(p0 + r) * TT + t) * 64 + c0) = v;
        }
    }
#pragma unroll
    for (int r_ = 0; r_ < 4; ++r_)
        path_state[(size_t)(p0 + q * 4 + r_) * 64 + d] = hold[r_];

    // ---- grid barrier ----
    bool isEdge = blockIdx.x < (LN / 16 + NN / 16);   // 384
    bar_arrive(barslot, isEdge);
    if (!isEdge) return;

    // ---- edge phase ----
    if (blockIdx.x < LN / 16)
        edge_body<KG>(e_idxs, e_Ab, e_Hbs, e_Hf, lwxT, lwhT, lbx, lbh, ptl,
                      pssb, link_state, blockIdx.x);
    else
        edge_body<K2G>(e_idxs, e_Ab, e_Hbs, e_Hf, dwxT, dwhT, dbx, dbh, ptn,
                       pssb, device_state, blockIdx.x - LN / 16);
}

// ---------------------------------------------------------------------------
// K_last: final pscan + fused readout (edge after last iter is dead work).
// ---------------------------------------------------------------------------
__global__ __launch_bounds__(256, 4) void k_last(
    const float* __restrict__ ls, const float* __restrict__ dst,
    const int* __restrict__ ltp, const int* __restrict__ ntp,
    const unsigned short* __restrict__ wxT, const unsigned short* __restrict__ whT,
    const float* __restrict__ bx, const float* __restrict__ bh,
    float* __restrict__ path_state,
    const float* __restrict__ rw1, const float* __restrict__ rb1,
    const float* __restrict__ rw2, const float* __restrict__ rb2,
    const float* __restrict__ rw3, const float* __restrict__ rb3,
    const float* __restrict__ cap, float* __restrict__ out)
{
    __shared__ __align__(16) unsigned short Xs[8][16][72];
    __shared__ __align__(16) unsigned short Hb[2][16][72];
    __shared__ __align__(16) float rw1s[2048];
    __shared__ __align__(16) float rw2s[512];
    __shared__ float rw3s[16], rb1s[32], rb2s[16];
    int tid = threadIdx.x;
    int p0 = blockIdx.x * 16;

    for (int i = tid; i < 2048; i += 256) rw1s[i] = rw1[i];
    for (int i = tid; i < 512; i += 256) rw2s[i] = rw2[i];
    if (tid < 16) rw3s[tid] = rw3[tid];
    if (tid < 32) rb1s[tid] = rb1[tid];
    if (tid < 16) rb2s[tid] = rb2[tid];
    {
        int r = tid >> 4, c0 = (tid & 15) * 4;
        float4 a = *(const float4*)(path_state + (size_t)(p0 + r) * 64 + c0);
        ushort4 u;
        u.x = f2bf(a.x); u.y = f2bf(a.y); u.z = f2bf(a.z); u.w = f2bf(a.w);
        *(ushort4*)&Hb[0][r][c0] = u;
    }
    {
        int t = tid >> 5, m = (tid >> 1) & 15, half = tid & 1;
        int gi = (p0 + m) * TT + t;
        int il = ltp[gi], in = ntp[gi];
        const float4* l4 = (const float4*)(ls + (size_t)il * 64 + half * 32);
        const float4* n4 = (const float4*)(dst + (size_t)in * 64 + half * 32);
#pragma unroll
        for (int j = 0; j < 8; ++j) {
            float4 a = l4[j], b = n4[j];
            ushort4 u;
            u.x = f2bf(a.x + b.x); u.y = f2bf(a.y + b.y);
            u.z = f2bf(a.z + b.z); u.w = f2bf(a.w + b.w);
            *(ushort4*)&Xs[t][m][half * 32 + j * 4] = u;
        }
    }
    int lane = tid & 63, w = tid >> 6;
    int c = lane & 15, q = lane >> 4;
    int d = 16 * w + c;
    short8b fx[3][2], fh[3][2];
#pragma unroll
    for (int g = 0; g < 3; ++g)
#pragma unroll
        for (int kt = 0; kt < 2; ++kt) {
            int off = (g * 64 + 16 * w + c) * 64 + kt * 32 + q * 8;
            fx[g][kt] = *(const short8b*)(wxT + off);
            fh[g][kt] = *(const short8b*)(whT + off);
        }
    float bz = bx[d] + bh[d];
    float br = bx[64 + d] + bh[64 + d];
    float bxc = bx[128 + d];
    float bhc = bh[128 + d];
    float hold[4];
#pragma unroll
    for (int r_ = 0; r_ < 4; ++r_)
        hold[r_] = path_state[(size_t)(p0 + q * 4 + r_) * 64 + d];
    __syncthreads();

    for (int t = 0; t < TT; ++t) {
        int rb = t & 1, wb = rb ^ 1;
        f32x4 ax[3], ah[3];
#pragma unroll
        for (int g = 0; g < 3; ++g) {
            ax[g] = (f32x4){0.f, 0.f, 0.f, 0.f};
            ah[g] = (f32x4){0.f, 0.f, 0.f, 0.f};
        }
#pragma unroll
        for (int kt = 0; kt < 2; ++kt) {
            short8b aX = *(const short8b*)&Xs[t][c][kt * 32 + q * 8];
            short8b aH = *(const short8b*)&Hb[rb][c][kt * 32 + q * 8];
#pragma unroll
            for (int g = 0; g < 3; ++g) {
                ax[g] = __builtin_amdgcn_mfma_f32_16x16x32_bf16(aX, fx[g][kt], ax[g], 0, 0, 0);
                ah[g] = __builtin_amdgcn_mfma_f32_16x16x32_bf16(aH, fh[g][kt], ah[g], 0, 0, 0);
            }
        }
#pragma unroll
        for (int r_ = 0; r_ < 4; ++r_) {
            float z  = sigmoidf_(ax[0][r_] + ah[0][r_] + bz);
            float rr = sigmoidf_(ax[1][r_] + ah[1][r_] + br);
            float cc = tanhf_(ax[2][r_] + bxc + rr * (ah[2][r_] + bhc));
            float hn = z * hold[r_] + (1.0f - z) * cc;
            hold[r_] = hn;
            Hb[wb][q * 4 + r_][d] = f2bf(hn);
        }
        __syncthreads();
        {
            int r = tid >> 4, c0 = (tid & 15) * 4;
            ushort4 v = *(const ushort4*)&Hb[wb][r][c0];
            *(ushort4*)&Xs[t][r][c0] = v;   // recycle Xs[t] as h-store
        }
    }
    // ===== fused readout: Xs[t][m][:] = h bf16 for all 8 steps =====
    __syncthreads();
    {
        int r = tid >> 1, hh = tid & 1;      // row r = m*8 + t
        int m = r >> 3, t = r & 7;
        short8b rowv[8];
#pragma unroll
        for (int j = 0; j < 8; ++j)
            rowv[j] = *(const short8b*)&Xs[t][m][j * 8];
        float a1[16];
#pragma unroll
        for (int i = 0; i < 16; ++i) a1[i] = 0.f;
#pragma unroll 4
        for (int k = 0; k < 64; ++k) {
            float x = bf2f((unsigned short)rowv[k >> 3][k & 7]);
            const float* wr = &rw1s[k * 32 + hh * 16];
            float4 wa = *(const float4*)(wr);
            float4 wb = *(const float4*)(wr + 4);
            float4 wc = *(const float4*)(wr + 8);
            float4 wd = *(const float4*)(wr + 12);
            a1[0]  += x * wa.x; a1[1]  += x * wa.y; a1[2]  += x * wa.z; a1[3]  += x * wa.w;
            a1[4]  += x * wb.x; a1[5]  += x * wb.y; a1[6]  += x * wb.z; a1[7]  += x * wb.w;
            a1[8]  += x * wc.x; a1[9]  += x * wc.y; a1[10] += x * wc.z; a1[11] += x * wc.w;
            a1[12] += x * wd.x; a1[13] += x * wd.y; a1[14] += x * wd.z; a1[15] += x * wd.w;
        }
#pragma unroll
        for (int i = 0; i < 16; ++i)
            a1[i] = fmaxf(a1[i] + rb1s[hh * 16 + i], 0.0f);
        float h1[32];
#pragma unroll
        for (int i = 0; i < 16; ++i) {
            float o = __shfl_xor(a1[i], 1);
            h1[hh * 16 + i] = a1[i];
            h1[(1 - hh) * 16 + i] = o;
        }
        float a2[8];
#pragma unroll
        for (int i = 0; i < 8; ++i) a2[i] = 0.f;
#pragma unroll 4
        for (int k = 0; k < 32; ++k) {
            float x = h1[k];
            const float* wr = &rw2s[k * 16 + hh * 8];
            float4 wa = *(const float4*)(wr);
            float4 wb = *(const float4*)(wr + 4);
            a2[0] += x * wa.x; a2[1] += x * wa.y; a2[2] += x * wa.z; a2[3] += x * wa.w;
            a2[4] += x * wb.x; a2[5] += x * wb.y; a2[6] += x * wb.z; a2[7] += x * wb.w;
        }
#pragma unroll
        for (int i = 0; i < 8; ++i)
            a2[i] = fmaxf(a2[i] + rb2s[hh * 8 + i], 0.0f);
        float h2[16];
#pragma unroll
        for (int i = 0; i < 8; ++i) {
            float o = __shfl_xor(a2[i], 1);
            h2[hh * 8 + i] = a2[i];
            h2[(1 - hh) * 8 + i] = o;
        }
        float a3 = rb3[0];
#pragma unroll
        for (int k = 0; k < 16; ++k) a3 += h2[k] * rw3s[k];
        float occ = softplusf_(a3);
        float dcon = occ * frcp(cap[ltp[(p0 + m) * TT + t]]);
        float s = dcon;
        s += __shfl_xor(s, 2);
        s += __shfl_xor(s, 4);
        s += __shfl_xor(s, 8);
        if ((tid & 15) == 0) out[p0 + m] = s;
    }
}

// ---------------------------------------------------------------------------
extern "C" void kernel_launch(void* const* d_in, const int* in_sizes, int n_in,
                              void* d_out, int out_size, void* d_ws, size_t ws_size,
                              hipStream_t stream) {
    const float* ft   = (const float*)d_in[0];
    const float* fpk  = (const float*)d_in[1];
    const float* fps  = (const float*)d_in[2];
    const float* cap  = (const float*)d_in[3];
    const float* pe_w1 = (const float*)d_in[4];
    const float* pe_b1 = (const float*)d_in[5];
    const float* pe_w2 = (const float*)d_in[6];
    const float* pe_b2 = (const float*)d_in[7];
    const float* le_w1 = (const float*)d_in[8];
    const float* le_b1 = (const float*)d_in[9];
    const float* le_w2 = (const float*)d_in[10];
    const float* le_b2 = (const float*)d_in[11];
    const float* de_w1 = (const float*)d_in[12];
    const float* de_b1 = (const float*)d_in[13];
    const float* de_w2 = (const float*)d_in[14];
    const float* de_b2 = (const float*)d_in[15];
    const float* pgru_wx = (const float*)d_in[16];
    const float* pgru_wh = (const float*)d_in[17];
    const float* pgru_bx = (const float*)d_in[18];
    const float* pgru_bh = (const float*)d_in[19];
    const float* lgru_wx = (const float*)d_in[20];
    const float* lgru_wh = (const float*)d_in[21];
    const float* lgru_bx = (const float*)d_in[22];
    const float* lgru_bh = (const float*)d_in[23];
    const float* dgru_wx = (const float*)d_in[24];
    const float* dgru_wh = (const float*)d_in[25];
    const float* dgru_bx = (const float*)d_in[26];
    const float* dgru_bh = (const float*)d_in[27];
    const float* ro_w1 = (const float*)d_in[28];
    const float* ro_b1 = (const float*)d_in[29];
    const float* ro_w2 = (const float*)d_in[30];
    const float* ro_b2 = (const float*)d_in[31];
    const float* ro_w3 = (const float*)d_in[32];
    const float* ro_b3 = (const float*)d_in[33];
    const int* ltp   = (const int*)d_in[34];
    const int* ntp   = (const int*)d_in[35];
    const int* ptl   = (const int*)d_in[36];
    const int* ptn   = (const int*)d_in[37];
    const int* ltn   = (const int*)d_in[38];
    const int* nodes = (const int*)d_in[39];
    const int* ldt   = (const int*)d_in[40];
    float* out = (float*)d_out;

    char* ws = (char*)d_ws;
    float* path_state = (float*)ws;      ws += (size_t)PN * 64 * 4;
    float* link_state = (float*)ws;      ws += (size_t)LN * 64 * 4;
    float* device_state = (float*)ws;    ws += (size_t)NN * 64 * 4;
    unsigned short* pssb = (unsigned short*)ws; ws += (size_t)PN * TT * 64 * 2;
    unsigned short* pwxT = (unsigned short*)ws; ws += 192 * 64 * 2;
    unsigned short* pwhT = (unsigned short*)ws; ws += 192 * 64 * 2;
    unsigned short* lwxT = (unsigned short*)ws; ws += 192 * 64 * 2;
    unsigned short* lwhT = (unsigned short*)ws; ws += 192 * 64 * 2;
    unsigned short* dwxT = (unsigned short*)ws; ws += 192 * 64 * 2;
    unsigned short* dwhT = (unsigned short*)ws; ws += 192 * 64 * 2;
    int* barbuf = (int*)ws;              ws += 4096;   // 7 slots x 576B

    hipMemsetAsync(barbuf, 0, 4096, stream);

    k_setup<<<1568, 256, 0, stream>>>(ft, fpk, fps, cap, ptl, ldt,
                                      pe_w1, pe_b1, pe_w2, pe_b2,
                                      le_w1, le_b1, le_w2, le_b2,
                                      pgru_wx, pgru_wh, lgru_wx, lgru_wh,
                                      dgru_wx, dgru_wh,
                                      pwxT, pwhT, lwxT, lwhT, dwxT, dwhT,
                                      path_state, link_state);
    k_device_encode<<<NN / 4, 256, 0, stream>>>(link_state, ltn, nodes, de_w1,
                                                de_b1, de_w2, de_b2, device_state);
    for (int it = 0; it < ITER - 1; ++it) {
        k_iter<<<GB, 256, 0, stream>>>(
            link_state, device_state, ltp, ntp, pwxT, pwhT, pgru_bx, pgru_bh,
            path_state, pssb,
            lwxT, lwhT, lgru_bx, lgru_bh, ptl,
            dwxT, dwhT, dgru_bx, dgru_bh, ptn,
            link_state, device_state, barbuf + it * 144);
    }
    k_last<<<GB, 256, 0, stream>>>(
        link_state, device_state, ltp, ntp, pwxT, pwhT, pgru_bx, pgru_bh,
        path_state, ro_w1, ro_b1, ro_w2, ro_b2, ro_w3, ro_b3, cap, out);
}

// Round 8
// 405.271 us; speedup vs baseline: 4.2410x; 4.2410x over previous
//
#include <hip/hip_runtime.h>
#include <hip/hip_bf16.h>

// Problem constants
static constexpr int PN = 16384;  // paths
static constexpr int TT = 8;      // seq len
static constexpr int LN = 4096;   // links
static constexpr int KG = 16;     // path_to_link K
static constexpr int NN = 2048;   // nodes
static constexpr int K2G = 32;    // path_to_node K2
static constexpr int MG = 8;      // link_to_node M
static constexpr int ITER = 8;

typedef __attribute__((ext_vector_type(8))) short short8b;   // 8 bf16 (4 VGPRs)
typedef __attribute__((ext_vector_type(4))) float f32x4;

__device__ __forceinline__ float frcp(float x) {
    return __builtin_amdgcn_rcpf(x);   // v_rcp_f32, ~1ulp
}
__device__ __forceinline__ float sigmoidf_(float x) {
    return frcp(1.0f + __expf(-x));
}
__device__ __forceinline__ float tanhf_(float x) {
    return 1.0f - 2.0f * frcp(__expf(2.0f * x) + 1.0f);
}
__device__ __forceinline__ float softplusf_(float x) {
    return fmaxf(x, 0.0f) + log1pf(__expf(-fabsf(x)));
}
__device__ __forceinline__ unsigned short f2bf(float f) {
    unsigned int x = __float_as_uint(f);
    unsigned int r = (x + 0x7fffu + ((x >> 16) & 1u)) >> 16;
    return (unsigned short)r;
}
__device__ __forceinline__ float bf2f(unsigned short u) {
    return __uint_as_float(((unsigned int)u) << 16);
}

// ---------------------------------------------------------------------------
// K_setup: heterogeneous launch.
//   blocks [0,1024)    : path encoder, 16 rows/block, w2 in LDS
//   blocks [1024,1280) : link encoder, 16 rows/block, w2 in LDS
//   blocks [1280,1568) : 6x GRU weight transpose fp32[64][192]->bf16[192][64]
// ---------------------------------------------------------------------------
__global__ __launch_bounds__(256) void k_setup(
    const float* __restrict__ ft, const float* __restrict__ fpk,
    const float* __restrict__ fps, const float* __restrict__ cap,
    const int* __restrict__ ptl, const int* __restrict__ ldt,
    const float* __restrict__ pe_w1, const float* __restrict__ pe_b1,
    const float* __restrict__ pe_w2, const float* __restrict__ pe_b2,
    const float* __restrict__ le_w1, const float* __restrict__ le_b1,
    const float* __restrict__ le_w2, const float* __restrict__ le_b2,
    const float* __restrict__ pgru_wx, const float* __restrict__ pgru_wh,
    const float* __restrict__ lgru_wx, const float* __restrict__ lgru_wh,
    const float* __restrict__ dgru_wx, const float* __restrict__ dgru_wh,
    unsigned short* __restrict__ pwxT, unsigned short* __restrict__ pwhT,
    unsigned short* __restrict__ lwxT, unsigned short* __restrict__ lwhT,
    unsigned short* __restrict__ dwxT, unsigned short* __restrict__ dwhT,
    float* __restrict__ path_state, float* __restrict__ link_state)
{
    int b = blockIdx.x;
    int tid = threadIdx.x;
    if (b >= 1280) {
        const float* srcs[6] = {pgru_wx, pgru_wh, lgru_wx, lgru_wh, dgru_wx, dgru_wh};
        unsigned short* dsts[6] = {pwxT, pwhT, lwxT, lwhT, dwxT, dwhT};
        int i = (b - 1280) * 256 + tid;     // 0 .. 6*12288-1
        int mi = i / 12288, o = i - mi * 12288;
        int n = o >> 6, k = o & 63;
        dsts[mi][o] = f2bf(srcs[mi][k * 192 + n]);
        return;
    }
    __shared__ __align__(16) float w2s[4096];
    __shared__ float w1s[192], b1s[64], b2s[64];
    __shared__ float h1s[4][64];
    bool isPath = (b < 1024);
    const float* w1p = isPath ? pe_w1 : le_w1;
    const float* b1p = isPath ? pe_b1 : le_b1;
    const float* w2p = isPath ? pe_w2 : le_w2;
    const float* b2p = isPath ? pe_b2 : le_b2;
    for (int i = tid; i < 4096; i += 256) w2s[i] = w2p[i];
    if (tid < 192) w1s[tid] = w1p[tid];
    if (tid < 64) { b1s[tid] = b1p[tid]; b2s[tid] = b2p[tid]; }
    __syncthreads();
    int rl = tid >> 6, d = tid & 63;
    int base = (isPath ? b : (b - 1024)) * 16;
    for (int rp = 0; rp < 4; ++rp) {
        int row = base + rp * 4 + rl;
        float h;
        if (isPath) {
            float x0 = ft[row]  * 1e-4f;
            float x1 = fpk[row] * 1e-3f;
            float x2 = fps[row] * 1e-3f;
            h = b1s[d] + x0 * w1s[d] + x1 * w1s[64 + d] + x2 * w1s[128 + d];
        } else {
            float v = 0.0f;
            if (d < 16) v = ft[ptl[(row * 16 + d) * 2]];
            v += __shfl_down(v, 8);
            v += __shfl_down(v, 4);
            v += __shfl_down(v, 2);
            v += __shfl_down(v, 1);
            float ssum = __shfl(v, 0);
            float cv = cap[row];
            float load = ssum * frcp(cv * 1e9f);
            float x2 = (ldt[row] == 0) ? 1.0f : 0.0f;
            h = b1s[d] + cv * 0.01f * w1s[d] + load * w1s[64 + d] + x2 * w1s[128 + d];
        }
        h1s[rl][d] = fmaxf(h, 0.0f);
        __syncthreads();
        float acc = b2s[d];
#pragma unroll 8
        for (int k = 0; k < 64; ++k) acc += h1s[rl][k] * w2s[k * 64 + d];
        float* dst = isPath ? path_state : link_state;
        dst[(size_t)row * 64 + d] = fmaxf(acc, 0.0f);
        __syncthreads();
    }
}

// ---------------------------------------------------------------------------
// K3: device encoder, w2 staged in LDS
// ---------------------------------------------------------------------------
__global__ __launch_bounds__(256) void k_device_encode(
    const float* __restrict__ link_state, const int* __restrict__ ltn,
    const int* __restrict__ nodes,
    const float* __restrict__ w1, const float* __restrict__ b1,
    const float* __restrict__ w2, const float* __restrict__ b2,
    float* __restrict__ device_state)
{
    __shared__ __align__(16) float w2s[4096];
    __shared__ float h1s[4][64];
    int tid = threadIdx.x;
    for (int i = tid; i < 4096; i += 256) w2s[i] = w2[i];
    int rl = tid >> 6, d = tid & 63;
    int row = blockIdx.x * 4 + rl;
    float s = 0.0f;
#pragma unroll
    for (int m = 0; m < MG; ++m)
        s += link_state[(size_t)ltn[row * MG + m] * 64 + d];
#pragma unroll
    for (int o = 32; o > 0; o >>= 1) s += __shfl_xor(s, o);
    float dlm = s * (1.0f / 64.0f);
    float enc = (nodes[row] == 0) ? 1.0f : 0.0f;
    float h = b1[d] + enc * w1[d] + dlm * w1[64 + d];
    h1s[rl][d] = fmaxf(h, 0.0f);
    __syncthreads();
    float acc = b2[d];
#pragma unroll 8
    for (int k = 0; k < 64; ++k) acc += h1s[rl][k] * w2s[k * 64 + d];
    device_state[(size_t)row * 64 + d] = fmaxf(acc, 0.0f);
}

// ---------------------------------------------------------------------------
// K4: fused x-gather + xproj + 8-step GRU scan (+ fused readout when LAST).
// 16 paths/block (1024 blocks = 4/CU). h-state in registers, dbuf bf16 Hb,
// one barrier/step. Gather: 16 lanes per 256B row (max coalescing), indices
// staged in LDS. Hb[0] seeded from hold registers (no second global pass).
// ---------------------------------------------------------------------------
template <bool LAST>
__global__ __launch_bounds__(256, 4) void k_pscan(
    const float* __restrict__ ls, const float* __restrict__ dst,
    const int* __restrict__ ltp, const int* __restrict__ ntp,
    const unsigned short* __restrict__ wxT,   // bf16 [192][64]
    const unsigned short* __restrict__ whT,   // bf16 [192][64]
    const float* __restrict__ bx, const float* __restrict__ bh,
    float* __restrict__ path_state, unsigned short* __restrict__ pssb,
    const float* __restrict__ rw1, const float* __restrict__ rb1,
    const float* __restrict__ rw2, const float* __restrict__ rb2,
    const float* __restrict__ rw3, const float* __restrict__ rb3,
    const float* __restrict__ cap, float* __restrict__ out)
{
    __shared__ __align__(16) unsigned short Xs[8][16][72];  // bf16 x / h-store
    __shared__ __align__(16) unsigned short Hb[2][16][72];  // bf16 h dbuf
    __shared__ int sIdx[256];                               // 128 pairs x {il,in}
    __shared__ __align__(16) float rw1s[2048];
    __shared__ __align__(16) float rw2s[512];
    __shared__ float rw3s[16], rb1s[32], rb2s[16];
    int tid = threadIdx.x;
    int p0 = blockIdx.x * 16;

    if (LAST) {
        for (int i = tid; i < 2048; i += 256) rw1s[i] = rw1[i];
        for (int i = tid; i < 512; i += 256) rw2s[i] = rw2[i];
        if (tid < 16) rw3s[tid] = rw3[tid];
        if (tid < 32) rb1s[tid] = rb1[tid];
        if (tid < 16) rb2s[tid] = rb2[tid];
    }
    // stage gather indices: pair pi=(m,t), sIdx[2*pi]=ltp, sIdx[2*pi+1]=ntp
    {
        int pi = tid >> 1;
        int m = pi & 15, t = pi >> 4;
        int gi = (p0 + m) * TT + t;
        sIdx[tid] = (tid & 1) ? ntp[gi] : ltp[gi];
    }
    __syncthreads();
    // gather x = ls[il] + dst[in] -> bf16 Xs[t][m][:]; 16 lanes per row
    {
        int j = tid & 15;          // float4 index within row
        int g = tid >> 4;          // group 0..15
#pragma unroll
        for (int ro = 0; ro < 8; ++ro) {
            int pi = ro * 16 + g;  // t = ro, m = g
            int il = sIdx[pi * 2];
            int in = sIdx[pi * 2 + 1];
            float4 a = *(const float4*)(ls + (size_t)il * 64 + j * 4);
            float4 b = *(const float4*)(dst + (size_t)in * 64 + j * 4);
            ushort4 u;
            u.x = f2bf(a.x + b.x); u.y = f2bf(a.y + b.y);
            u.z = f2bf(a.z + b.z); u.w = f2bf(a.w + b.w);
            *(ushort4*)&Xs[ro][g][j * 4] = u;
        }
    }

    int lane = tid & 63, w = tid >> 6;
    int c = lane & 15, q = lane >> 4;
    int d = 16 * w + c;
    short8b fx[3][2], fh[3][2];
#pragma unroll
    for (int g = 0; g < 3; ++g)
#pragma unroll
        for (int kt = 0; kt < 2; ++kt) {
            int off = (g * 64 + 16 * w + c) * 64 + kt * 32 + q * 8;
            fx[g][kt] = *(const short8b*)(wxT + off);
            fh[g][kt] = *(const short8b*)(whT + off);
        }
    float bz = bx[d] + bh[d];
    float br = bx[64 + d] + bh[64 + d];
    float bxc = bx[128 + d];
    float bhc = bh[128 + d];
    float hold[4];
#pragma unroll
    for (int r_ = 0; r_ < 4; ++r_) {
        hold[r_] = path_state[(size_t)(p0 + q * 4 + r_) * 64 + d];
        Hb[0][q * 4 + r_][d] = f2bf(hold[r_]);   // seed h0 from registers
    }
    __syncthreads();

    for (int t = 0; t < TT; ++t) {
        int rb = t & 1, wb = rb ^ 1;
        f32x4 ax[3], ah[3];
#pragma unroll
        for (int g = 0; g < 3; ++g) {
            ax[g] = (f32x4){0.f, 0.f, 0.f, 0.f};
            ah[g] = (f32x4){0.f, 0.f, 0.f, 0.f};
        }
#pragma unroll
        for (int kt = 0; kt < 2; ++kt) {
            short8b aX = *(const short8b*)&Xs[t][c][kt * 32 + q * 8];
            short8b aH = *(const short8b*)&Hb[rb][c][kt * 32 + q * 8];
#pragma unroll
            for (int g = 0; g < 3; ++g) {
                ax[g] = __builtin_amdgcn_mfma_f32_16x16x32_bf16(aX, fx[g][kt], ax[g], 0, 0, 0);
                ah[g] = __builtin_amdgcn_mfma_f32_16x16x32_bf16(aH, fh[g][kt], ah[g], 0, 0, 0);
            }
        }
#pragma unroll
        for (int r_ = 0; r_ < 4; ++r_) {
            float z  = sigmoidf_(ax[0][r_] + ah[0][r_] + bz);
            float rr = sigmoidf_(ax[1][r_] + ah[1][r_] + br);
            float cc = tanhf_(ax[2][r_] + bxc + rr * (ah[2][r_] + bhc));
            float hn = z * hold[r_] + (1.0f - z) * cc;
            hold[r_] = hn;
            Hb[wb][q * 4 + r_][d] = f2bf(hn);
        }
        __syncthreads();
        // cooperative copy of h_t: to Xs[t] (LAST) or coalesced pssb store
        {
            int r = tid >> 4, c0 = (tid & 15) * 4;
            ushort4 v = *(const ushort4*)&Hb[wb][r][c0];
            if (LAST) {
                *(ushort4*)&Xs[t][r][c0] = v;
            } else {
                *(ushort4*)(pssb + ((size_t)(p0 + r) * TT + t) * 64 + c0) = v;
            }
        }
    }
    if (!LAST) {
#pragma unroll
        for (int r_ = 0; r_ < 4; ++r_)
            path_state[(size_t)(p0 + q * 4 + r_) * 64 + d] = hold[r_];
        return;
    }
    // ===== fused readout: Xs[t][m][:] = h bf16 for all 8 steps =====
    __syncthreads();
    {
        int r = tid >> 1, hh = tid & 1;      // row r = m*8 + t
        int m = r >> 3, t = r & 7;
        short8b rowv[8];
#pragma unroll
        for (int j = 0; j < 8; ++j)
            rowv[j] = *(const short8b*)&Xs[t][m][j * 8];
        float a1[16];
#pragma unroll
        for (int i = 0; i < 16; ++i) a1[i] = 0.f;
#pragma unroll 4
        for (int k = 0; k < 64; ++k) {
            float x = bf2f((unsigned short)rowv[k >> 3][k & 7]);
            const float* wr = &rw1s[k * 32 + hh * 16];
            float4 wa = *(const float4*)(wr);
            float4 wb = *(const float4*)(wr + 4);
            float4 wc = *(const float4*)(wr + 8);
            float4 wd = *(const float4*)(wr + 12);
            a1[0]  += x * wa.x; a1[1]  += x * wa.y; a1[2]  += x * wa.z; a1[3]  += x * wa.w;
            a1[4]  += x * wb.x; a1[5]  += x * wb.y; a1[6]  += x * wb.z; a1[7]  += x * wb.w;
            a1[8]  += x * wc.x; a1[9]  += x * wc.y; a1[10] += x * wc.z; a1[11] += x * wc.w;
            a1[12] += x * wd.x; a1[13] += x * wd.y; a1[14] += x * wd.z; a1[15] += x * wd.w;
        }
#pragma unroll
        for (int i = 0; i < 16; ++i)
            a1[i] = fmaxf(a1[i] + rb1s[hh * 16 + i], 0.0f);
        float h1[32];
#pragma unroll
        for (int i = 0; i < 16; ++i) {
            float o = __shfl_xor(a1[i], 1);
            h1[hh * 16 + i] = a1[i];
            h1[(1 - hh) * 16 + i] = o;
        }
        float a2[8];
#pragma unroll
        for (int i = 0; i < 8; ++i) a2[i] = 0.f;
#pragma unroll 4
        for (int k = 0; k < 32; ++k) {
            float x = h1[k];
            const float* wr = &rw2s[k * 16 + hh * 8];
            float4 wa = *(const float4*)(wr);
            float4 wb = *(const float4*)(wr + 4);
            a2[0] += x * wa.x; a2[1] += x * wa.y; a2[2] += x * wa.z; a2[3] += x * wa.w;
            a2[4] += x * wb.x; a2[5] += x * wb.y; a2[6] += x * wb.z; a2[7] += x * wb.w;
        }
#pragma unroll
        for (int i = 0; i < 8; ++i)
            a2[i] = fmaxf(a2[i] + rb2s[hh * 8 + i], 0.0f);
        float h2[16];
#pragma unroll
        for (int i = 0; i < 8; ++i) {
            float o = __shfl_xor(a2[i], 1);
            h2[hh * 8 + i] = a2[i];
            h2[(1 - hh) * 8 + i] = o;
        }
        float a3 = rb3[0];
#pragma unroll
        for (int k = 0; k < 16; ++k) a3 += h2[k] * rw3s[k];
        float occ = softplusf_(a3);
        float dcon = occ * frcp(cap[ltp[(p0 + m) * TT + t]]);
        float s = dcon;
        s += __shfl_xor(s, 2);
        s += __shfl_xor(s, 4);
        s += __shfl_xor(s, 8);
        if ((tid & 15) == 0) out[p0 + m] = s;
    }
}

// ---------------------------------------------------------------------------
// K6: merged link+device GRU update. Template Kg => fully unrolled gathers.
// ---------------------------------------------------------------------------
template <int Kg>
__device__ __forceinline__ void edge_body(
    const unsigned short* __restrict__ wxT, const unsigned short* __restrict__ whT,
    const float* __restrict__ bx, const float* __restrict__ bh,
    const int* __restrict__ p2e, const unsigned short* __restrict__ pssb,
    float* __restrict__ state, int blk)
{
    __shared__ int idxs[16 * Kg * 2];
    __shared__ __align__(16) unsigned short Ab[16][72];
    __shared__ __align__(16) unsigned short Hbs[16][72];
    __shared__ __align__(16) float Hf[16][68];
    int tid = threadIdx.x;
    int r0 = blk * 16;
    for (int i = tid; i < 16 * Kg * 2; i += 256)
        idxs[i] = p2e[(size_t)r0 * Kg * 2 + i];
    __syncthreads();
    {
        int r = tid >> 4, c4 = (tid & 15) * 4;
        int row = r0 + r;
        float4 s = {0.f, 0.f, 0.f, 0.f};
#pragma unroll
        for (int k = 0; k < Kg; ++k) {
            int pi = idxs[(r * Kg + k) * 2];
            int ti = idxs[(r * Kg + k) * 2 + 1];
            ushort4 v = *(const ushort4*)(pssb + ((size_t)pi * TT + ti - 1) * 64 + c4);
            s.x += bf2f(v.x); s.y += bf2f(v.y);
            s.z += bf2f(v.z); s.w += bf2f(v.w);
        }
        ushort4 ua;
        ua.x = f2bf(s.x); ua.y = f2bf(s.y); ua.z = f2bf(s.z); ua.w = f2bf(s.w);
        *(ushort4*)&Ab[r][c4] = ua;
        float4 hv = *(const float4*)(state + (size_t)row * 64 + c4);
        *(float4*)&Hf[r][c4] = hv;
        ushort4 uh;
        uh.x = f2bf(hv.x); uh.y = f2bf(hv.y); uh.z = f2bf(hv.z); uh.w = f2bf(hv.w);
        *(ushort4*)&Hbs[r][c4] = uh;
    }
    __syncthreads();
    int lane = tid & 63, w = tid >> 6;
    int c = lane & 15, q = lane >> 4;
    int d = 16 * w + c;
    short8b fx[3][2], fh[3][2];
#pragma unroll
    for (int g = 0; g < 3; ++g)
#pragma unroll
        for (int kt = 0; kt < 2; ++kt) {
            int off = (g * 64 + 16 * w + c) * 64 + kt * 32 + q * 8;
            fx[g][kt] = *(const short8b*)(wxT + off);
            fh[g][kt] = *(const short8b*)(whT + off);
        }
    f32x4 ax[3], ah[3];
#pragma unroll
    for (int g = 0; g < 3; ++g) {
        ax[g] = (f32x4){0.f, 0.f, 0.f, 0.f};
        ah[g] = (f32x4){0.f, 0.f, 0.f, 0.f};
    }
#pragma unroll
    for (int kt = 0; kt < 2; ++kt) {
        short8b aA = *(const short8b*)&Ab[c][kt * 32 + q * 8];
        short8b aH = *(const short8b*)&Hbs[c][kt * 32 + q * 8];
#pragma unroll
        for (int g = 0; g < 3; ++g) {
            ax[g] = __builtin_amdgcn_mfma_f32_16x16x32_bf16(aA, fx[g][kt], ax[g], 0, 0, 0);
            ah[g] = __builtin_amdgcn_mfma_f32_16x16x32_bf16(aH, fh[g][kt], ah[g], 0, 0, 0);
        }
    }
    float bz = bx[d] + bh[d];
    float br = bx[64 + d] + bh[64 + d];
    float bxc = bx[128 + d];
    float bhc = bh[128 + d];
#pragma unroll
    for (int r = 0; r < 4; ++r) {
        int m = q * 4 + r;
        float z  = sigmoidf_(ax[0][r] + ah[0][r] + bz);
        float rr = sigmoidf_(ax[1][r] + ah[1][r] + br);
        float cc = tanhf_(ax[2][r] + bxc + rr * (ah[2][r] + bhc));
        float hn = z * Hf[m][d] + (1.0f - z) * cc;
        state[(size_t)(r0 + m) * 64 + d] = hn;
    }
}

__global__ __launch_bounds__(256) void k_edge_merged(
    const unsigned short* __restrict__ lwxT, const unsigned short* __restrict__ lwhT,
    const float* __restrict__ lbx, const float* __restrict__ lbh,
    const int* __restrict__ ptl,
    const unsigned short* __restrict__ dwxT, const unsigned short* __restrict__ dwhT,
    const float* __restrict__ dbx, const float* __restrict__ dbh,
    const int* __restrict__ ptn,
    const unsigned short* __restrict__ pssb,
    float* __restrict__ link_state, float* __restrict__ device_state)
{
    int b = blockIdx.x;
    if (b < LN / 16) {
        edge_body<KG>(lwxT, lwhT, lbx, lbh, ptl, pssb, link_state, b);
    } else {
        edge_body<K2G>(dwxT, dwhT, dbx, dbh, ptn, pssb, device_state, b - LN / 16);
    }
}

// ---------------------------------------------------------------------------
extern "C" void kernel_launch(void* const* d_in, const int* in_sizes, int n_in,
                              void* d_out, int out_size, void* d_ws, size_t ws_size,
                              hipStream_t stream) {
    const float* ft   = (const float*)d_in[0];
    const float* fpk  = (const float*)d_in[1];
    const float* fps  = (const float*)d_in[2];
    const float* cap  = (const float*)d_in[3];
    const float* pe_w1 = (const float*)d_in[4];
    const float* pe_b1 = (const float*)d_in[5];
    const float* pe_w2 = (const float*)d_in[6];
    const float* pe_b2 = (const float*)d_in[7];
    const float* le_w1 = (const float*)d_in[8];
    const float* le_b1 = (const float*)d_in[9];
    const float* le_w2 = (const float*)d_in[10];
    const float* le_b2 = (const float*)d_in[11];
    const float* de_w1 = (const float*)d_in[12];
    const float* de_b1 = (const float*)d_in[13];
    const float* de_w2 = (const float*)d_in[14];
    const float* de_b2 = (const float*)d_in[15];
    const float* pgru_wx = (const float*)d_in[16];
    const float* pgru_wh = (const float*)d_in[17];
    const float* pgru_bx = (const float*)d_in[18];
    const float* pgru_bh = (const float*)d_in[19];
    const float* lgru_wx = (const float*)d_in[20];
    const float* lgru_wh = (const float*)d_in[21];
    const float* lgru_bx = (const float*)d_in[22];
    const float* lgru_bh = (const float*)d_in[23];
    const float* dgru_wx = (const float*)d_in[24];
    const float* dgru_wh = (const float*)d_in[25];
    const float* dgru_bx = (const float*)d_in[26];
    const float* dgru_bh = (const float*)d_in[27];
    const float* ro_w1 = (const float*)d_in[28];
    const float* ro_b1 = (const float*)d_in[29];
    const float* ro_w2 = (const float*)d_in[30];
    const float* ro_b2 = (const float*)d_in[31];
    const float* ro_w3 = (const float*)d_in[32];
    const float* ro_b3 = (const float*)d_in[33];
    const int* ltp   = (const int*)d_in[34];
    const int* ntp   = (const int*)d_in[35];
    const int* ptl   = (const int*)d_in[36];
    const int* ptn   = (const int*)d_in[37];
    const int* ltn   = (const int*)d_in[38];
    const int* nodes = (const int*)d_in[39];
    const int* ldt   = (const int*)d_in[40];
    float* out = (float*)d_out;

    char* ws = (char*)d_ws;
    float* path_state = (float*)ws;      ws += (size_t)PN * 64 * 4;
    float* link_state = (float*)ws;      ws += (size_t)LN * 64 * 4;
    float* device_state = (float*)ws;    ws += (size_t)NN * 64 * 4;
    unsigned short* pssb = (unsigned short*)ws; ws += (size_t)PN * TT * 64 * 2;
    unsigned short* pwxT = (unsigned short*)ws; ws += 192 * 64 * 2;
    unsigned short* pwhT = (unsigned short*)ws; ws += 192 * 64 * 2;
    unsigned short* lwxT = (unsigned short*)ws; ws += 192 * 64 * 2;
    unsigned short* lwhT = (unsigned short*)ws; ws += 192 * 64 * 2;
    unsigned short* dwxT = (unsigned short*)ws; ws += 192 * 64 * 2;
    unsigned short* dwhT = (unsigned short*)ws; ws += 192 * 64 * 2;

    k_setup<<<1568, 256, 0, stream>>>(ft, fpk, fps, cap, ptl, ldt,
                                      pe_w1, pe_b1, pe_w2, pe_b2,
                                      le_w1, le_b1, le_w2, le_b2,
                                      pgru_wx, pgru_wh, lgru_wx, lgru_wh,
                                      dgru_wx, dgru_wh,
                                      pwxT, pwhT, lwxT, lwhT, dwxT, dwhT,
                                      path_state, link_state);
    k_device_encode<<<NN / 4, 256, 0, stream>>>(link_state, ltn, nodes, de_w1,
                                                de_b1, de_w2, de_b2, device_state);
    for (int it = 0; it < ITER - 1; ++it) {
        k_pscan<false><<<PN / 16, 256, 0, stream>>>(
            link_state, device_state, ltp, ntp, pwxT, pwhT, pgru_bx, pgru_bh,
            path_state, pssb, ro_w1, ro_b1, ro_w2, ro_b2, ro_w3, ro_b3, cap, out);
        k_edge_merged<<<LN / 16 + NN / 16, 256, 0, stream>>>(
            lwxT, lwhT, lgru_bx, lgru_bh, ptl,
            dwxT, dwhT, dgru_bx, dgru_bh, ptn,
            pssb, link_state, device_state);
    }
    // final iteration: pscan + fused readout (edge update after it is dead work)
    k_pscan<true><<<PN / 16, 256, 0, stream>>>(
        link_state, device_state, ltp, ntp, pwxT, pwhT, pgru_bx, pgru_bh,
        path_state, pssb, ro_w1, ro_b1, ro_w2, ro_b2, ro_w3, ro_b3, cap, out);
}

// Round 9
// 399.275 us; speedup vs baseline: 4.3047x; 1.0150x over previous
//
#include <hip/hip_runtime.h>
#include <hip/hip_bf16.h>

// Problem constants
static constexpr int PN = 16384;  // paths
static constexpr int TT = 8;      // seq len
static constexpr int LN = 4096;   // links
static constexpr int KG = 16;     // path_to_link K
static constexpr int NN = 2048;   // nodes
static constexpr int K2G = 32;    // path_to_node K2
static constexpr int MG = 8;      // link_to_node M
static constexpr int ITER = 8;

typedef __attribute__((ext_vector_type(8))) short short8b;   // 8 bf16 (4 VGPRs)
typedef __attribute__((ext_vector_type(4))) float f32x4;

__device__ __forceinline__ float frcp(float x) {
    return __builtin_amdgcn_rcpf(x);   // v_rcp_f32, ~1ulp
}
__device__ __forceinline__ float sigmoidf_(float x) {
    return frcp(1.0f + __expf(-x));
}
__device__ __forceinline__ float tanhf_(float x) {
    return 1.0f - 2.0f * frcp(__expf(2.0f * x) + 1.0f);
}
__device__ __forceinline__ float softplusf_(float x) {
    return fmaxf(x, 0.0f) + log1pf(__expf(-fabsf(x)));
}
__device__ __forceinline__ unsigned short f2bf(float f) {
    unsigned int x = __float_as_uint(f);
    unsigned int r = (x + 0x7fffu + ((x >> 16) & 1u)) >> 16;
    return (unsigned short)r;
}
// packed RNE f32x2 -> bf16x2 (v_cvt_pk_bf16_f32 on gfx950)
__device__ __forceinline__ unsigned int pk2bf(float a, float b) {
    union { __hip_bfloat162 h; unsigned int u; } cvt;
    cvt.h = __float22bfloat162_rn(float2{a, b});
    return cvt.u;
}
__device__ __forceinline__ float bf2f(unsigned short u) {
    return __uint_as_float(((unsigned int)u) << 16);
}

// ---------------------------------------------------------------------------
// K_setup: heterogeneous launch.
//   blocks [0,1024)    : path encoder, 16 rows/block, w2 in LDS
//   blocks [1024,1280) : link encoder, 16 rows/block, w2 in LDS
//   blocks [1280,1568) : 6x GRU weight transpose fp32[64][192]->bf16[192][64]
// ---------------------------------------------------------------------------
__global__ __launch_bounds__(256) void k_setup(
    const float* __restrict__ ft, const float* __restrict__ fpk,
    const float* __restrict__ fps, const float* __restrict__ cap,
    const int* __restrict__ ptl, const int* __restrict__ ldt,
    const float* __restrict__ pe_w1, const float* __restrict__ pe_b1,
    const float* __restrict__ pe_w2, const float* __restrict__ pe_b2,
    const float* __restrict__ le_w1, const float* __restrict__ le_b1,
    const float* __restrict__ le_w2, const float* __restrict__ le_b2,
    const float* __restrict__ pgru_wx, const float* __restrict__ pgru_wh,
    const float* __restrict__ lgru_wx, const float* __restrict__ lgru_wh,
    const float* __restrict__ dgru_wx, const float* __restrict__ dgru_wh,
    unsigned short* __restrict__ pwxT, unsigned short* __restrict__ pwhT,
    unsigned short* __restrict__ lwxT, unsigned short* __restrict__ lwhT,
    unsigned short* __restrict__ dwxT, unsigned short* __restrict__ dwhT,
    float* __restrict__ path_state, float* __restrict__ link_state)
{
    int b = blockIdx.x;
    int tid = threadIdx.x;
    if (b >= 1280) {
        const float* srcs[6] = {pgru_wx, pgru_wh, lgru_wx, lgru_wh, dgru_wx, dgru_wh};
        unsigned short* dsts[6] = {pwxT, pwhT, lwxT, lwhT, dwxT, dwhT};
        int i = (b - 1280) * 256 + tid;     // 0 .. 6*12288-1
        int mi = i / 12288, o = i - mi * 12288;
        int n = o >> 6, k = o & 63;
        dsts[mi][o] = f2bf(srcs[mi][k * 192 + n]);
        return;
    }
    __shared__ __align__(16) float w2s[4096];
    __shared__ float w1s[192], b1s[64], b2s[64];
    __shared__ float h1s[4][64];
    bool isPath = (b < 1024);
    const float* w1p = isPath ? pe_w1 : le_w1;
    const float* b1p = isPath ? pe_b1 : le_b1;
    const float* w2p = isPath ? pe_w2 : le_w2;
    const float* b2p = isPath ? pe_b2 : le_b2;
    for (int i = tid; i < 4096; i += 256) w2s[i] = w2p[i];
    if (tid < 192) w1s[tid] = w1p[tid];
    if (tid < 64) { b1s[tid] = b1p[tid]; b2s[tid] = b2p[tid]; }
    __syncthreads();
    int rl = tid >> 6, d = tid & 63;
    int base = (isPath ? b : (b - 1024)) * 16;
    for (int rp = 0; rp < 4; ++rp) {
        int row = base + rp * 4 + rl;
        float h;
        if (isPath) {
            float x0 = ft[row]  * 1e-4f;
            float x1 = fpk[row] * 1e-3f;
            float x2 = fps[row] * 1e-3f;
            h = b1s[d] + x0 * w1s[d] + x1 * w1s[64 + d] + x2 * w1s[128 + d];
        } else {
            float v = 0.0f;
            if (d < 16) v = ft[ptl[(row * 16 + d) * 2]];
            v += __shfl_down(v, 8);
            v += __shfl_down(v, 4);
            v += __shfl_down(v, 2);
            v += __shfl_down(v, 1);
            float ssum = __shfl(v, 0);
            float cv = cap[row];
            float load = ssum * frcp(cv * 1e9f);
            float x2 = (ldt[row] == 0) ? 1.0f : 0.0f;
            h = b1s[d] + cv * 0.01f * w1s[d] + load * w1s[64 + d] + x2 * w1s[128 + d];
        }
        h1s[rl][d] = fmaxf(h, 0.0f);
        __syncthreads();
        float acc = b2s[d];
#pragma unroll 8
        for (int k = 0; k < 64; ++k) acc += h1s[rl][k] * w2s[k * 64 + d];
        float* dst = isPath ? path_state : link_state;
        dst[(size_t)row * 64 + d] = fmaxf(acc, 0.0f);
        __syncthreads();
    }
}

// ---------------------------------------------------------------------------
// K3: device encoder, w2 staged in LDS
// ---------------------------------------------------------------------------
__global__ __launch_bounds__(256) void k_device_encode(
    const float* __restrict__ link_state, const int* __restrict__ ltn,
    const int* __restrict__ nodes,
    const float* __restrict__ w1, const float* __restrict__ b1,
    const float* __restrict__ w2, const float* __restrict__ b2,
    float* __restrict__ device_state)
{
    __shared__ __align__(16) float w2s[4096];
    __shared__ float h1s[4][64];
    int tid = threadIdx.x;
    for (int i = tid; i < 4096; i += 256) w2s[i] = w2[i];
    int rl = tid >> 6, d = tid & 63;
    int row = blockIdx.x * 4 + rl;
    float s = 0.0f;
#pragma unroll
    for (int m = 0; m < MG; ++m)
        s += link_state[(size_t)ltn[row * MG + m] * 64 + d];
#pragma unroll
    for (int o = 32; o > 0; o >>= 1) s += __shfl_xor(s, o);
    float dlm = s * (1.0f / 64.0f);
    float enc = (nodes[row] == 0) ? 1.0f : 0.0f;
    float h = b1[d] + enc * w1[d] + dlm * w1[64 + d];
    h1s[rl][d] = fmaxf(h, 0.0f);
    __syncthreads();
    float acc = b2[d];
#pragma unroll 8
    for (int k = 0; k < 64; ++k) acc += h1s[rl][k] * w2s[k * 64 + d];
    device_state[(size_t)row * 64 + d] = fmaxf(acc, 0.0f);
}

// ---------------------------------------------------------------------------
// K4: fused x-gather + xproj + 8-step GRU scan (+ fused readout when LAST).
// 16 paths/block (1024 blocks = 4/CU). Bias-seeded accumulators, pk bf16
// conversions, aX software prefetch. One barrier per step.
// ---------------------------------------------------------------------------
template <bool LAST>
__global__ __launch_bounds__(256, 4) void k_pscan(
    const float* __restrict__ ls, const float* __restrict__ dst,
    const int* __restrict__ ltp, const int* __restrict__ ntp,
    const unsigned short* __restrict__ wxT,   // bf16 [192][64]
    const unsigned short* __restrict__ whT,   // bf16 [192][64]
    const float* __restrict__ bx, const float* __restrict__ bh,
    float* __restrict__ path_state, unsigned short* __restrict__ pssb,
    const float* __restrict__ rw1, const float* __restrict__ rb1,
    const float* __restrict__ rw2, const float* __restrict__ rb2,
    const float* __restrict__ rw3, const float* __restrict__ rb3,
    const float* __restrict__ cap, float* __restrict__ out)
{
    __shared__ __align__(16) unsigned short Xs[8][16][72];  // bf16 x / h-store
    __shared__ __align__(16) unsigned short Hb[2][16][72];  // bf16 h dbuf
    __shared__ int sIdx[256];                               // 128 pairs x {il,in}
    __shared__ __align__(16) float rw1s[2048];
    __shared__ __align__(16) float rw2s[512];
    __shared__ float rw3s[16], rb1s[32], rb2s[16];
    int tid = threadIdx.x;
    int p0 = blockIdx.x * 16;

    if (LAST) {
        for (int i = tid; i < 2048; i += 256) rw1s[i] = rw1[i];
        for (int i = tid; i < 512; i += 256) rw2s[i] = rw2[i];
        if (tid < 16) rw3s[tid] = rw3[tid];
        if (tid < 32) rb1s[tid] = rb1[tid];
        if (tid < 16) rb2s[tid] = rb2[tid];
    }
    // stage gather indices
    {
        int pi = tid >> 1;
        int m = pi & 15, t = pi >> 4;
        int gi = (p0 + m) * TT + t;
        sIdx[tid] = (tid & 1) ? ntp[gi] : ltp[gi];
    }
    __syncthreads();
    // gather x = ls[il] + dst[in] -> bf16 Xs[t][m][:]; 16 lanes per row
    {
        int j = tid & 15;          // float4 index within row
        int g = tid >> 4;          // group 0..15
#pragma unroll
        for (int ro = 0; ro < 8; ++ro) {
            int pi = ro * 16 + g;  // t = ro, m = g
            int il = sIdx[pi * 2];
            int in = sIdx[pi * 2 + 1];
            float4 a = *(const float4*)(ls + (size_t)il * 64 + j * 4);
            float4 b = *(const float4*)(dst + (size_t)in * 64 + j * 4);
            uint2 u;
            u.x = pk2bf(a.x + b.x, a.y + b.y);
            u.y = pk2bf(a.z + b.z, a.w + b.w);
            *(uint2*)&Xs[ro][g][j * 4] = u;
        }
    }

    int lane = tid & 63, w = tid >> 6;
    int c = lane & 15, q = lane >> 4;
    int d = 16 * w + c;
    short8b fx[3][2], fh[3][2];
#pragma unroll
    for (int g = 0; g < 3; ++g)
#pragma unroll
        for (int kt = 0; kt < 2; ++kt) {
            int off = (g * 64 + 16 * w + c) * 64 + kt * 32 + q * 8;
            fx[g][kt] = *(const short8b*)(wxT + off);
            fh[g][kt] = *(const short8b*)(whT + off);
        }
    float bz = bx[d] + bh[d];
    float br = bx[64 + d] + bh[64 + d];
    float bxc = bx[128 + d];
    float bhc = bh[128 + d];
    float hold[4];
#pragma unroll
    for (int r_ = 0; r_ < 4; ++r_) {
        hold[r_] = path_state[(size_t)(p0 + q * 4 + r_) * 64 + d];
        Hb[0][q * 4 + r_][d] = f2bf(hold[r_]);   // seed h0 from registers
    }
    __syncthreads();

    // aX prefetch registers
    short8b aXc0 = *(const short8b*)&Xs[0][c][q * 8];
    short8b aXc1 = *(const short8b*)&Xs[0][c][32 + q * 8];

    for (int t = 0; t < TT; ++t) {
        int rb = t & 1, wb = rb ^ 1;
        // bias-seeded accumulators
        f32x4 ax[3], ah[3];
        ax[0] = (f32x4){bz, bz, bz, bz};
        ax[1] = (f32x4){br, br, br, br};
        ax[2] = (f32x4){bxc, bxc, bxc, bxc};
        ah[0] = (f32x4){0.f, 0.f, 0.f, 0.f};
        ah[1] = (f32x4){0.f, 0.f, 0.f, 0.f};
        ah[2] = (f32x4){bhc, bhc, bhc, bhc};
        short8b aH0 = *(const short8b*)&Hb[rb][c][q * 8];
        short8b aH1 = *(const short8b*)&Hb[rb][c][32 + q * 8];
#pragma unroll
        for (int g = 0; g < 3; ++g) {
            ax[g] = __builtin_amdgcn_mfma_f32_16x16x32_bf16(aXc0, fx[g][0], ax[g], 0, 0, 0);
            ax[g] = __builtin_amdgcn_mfma_f32_16x16x32_bf16(aXc1, fx[g][1], ax[g], 0, 0, 0);
            ah[g] = __builtin_amdgcn_mfma_f32_16x16x32_bf16(aH0, fh[g][0], ah[g], 0, 0, 0);
            ah[g] = __builtin_amdgcn_mfma_f32_16x16x32_bf16(aH1, fh[g][1], ah[g], 0, 0, 0);
        }
        // prefetch next step's x fragments (hides ds_read under gate VALU)
        if (t < TT - 1) {
            aXc0 = *(const short8b*)&Xs[t + 1][c][q * 8];
            aXc1 = *(const short8b*)&Xs[t + 1][c][32 + q * 8];
        }
#pragma unroll
        for (int r_ = 0; r_ < 4; ++r_) {
            float z  = sigmoidf_(ax[0][r_] + ah[0][r_]);
            float rr = sigmoidf_(ax[1][r_] + ah[1][r_]);
            float cc = tanhf_(ax[2][r_] + rr * ah[2][r_]);
            float hn = cc + z * (hold[r_] - cc);
            hold[r_] = hn;
            Hb[wb][q * 4 + r_][d] = f2bf(hn);
        }
        __syncthreads();
        // cooperative copy of h_t: to Xs[t] (LAST) or coalesced pssb store
        {
            int r = tid >> 4, c0 = (tid & 15) * 4;
            ushort4 v = *(const ushort4*)&Hb[wb][r][c0];
            if (LAST) {
                *(ushort4*)&Xs[t][r][c0] = v;
            } else {
                *(ushort4*)(pssb + ((size_t)(p0 + r) * TT + t) * 64 + c0) = v;
            }
        }
    }
    if (!LAST) {
#pragma unroll
        for (int r_ = 0; r_ < 4; ++r_)
            path_state[(size_t)(p0 + q * 4 + r_) * 64 + d] = hold[r_];
        return;
    }
    // ===== fused readout: Xs[t][m][:] = h bf16 for all 8 steps =====
    __syncthreads();
    {
        int r = tid >> 1, hh = tid & 1;      // row r = m*8 + t
        int m = r >> 3, t = r & 7;
        short8b rowv[8];
#pragma unroll
        for (int j = 0; j < 8; ++j)
            rowv[j] = *(const short8b*)&Xs[t][m][j * 8];
        float a1[16];
#pragma unroll
        for (int i = 0; i < 16; ++i) a1[i] = 0.f;
#pragma unroll 4
        for (int k = 0; k < 64; ++k) {
            float x = bf2f((unsigned short)rowv[k >> 3][k & 7]);
            const float* wr = &rw1s[k * 32 + hh * 16];
            float4 wa = *(const float4*)(wr);
            float4 wb = *(const float4*)(wr + 4);
            float4 wc = *(const float4*)(wr + 8);
            float4 wd = *(const float4*)(wr + 12);
            a1[0]  += x * wa.x; a1[1]  += x * wa.y; a1[2]  += x * wa.z; a1[3]  += x * wa.w;
            a1[4]  += x * wb.x; a1[5]  += x * wb.y; a1[6]  += x * wb.z; a1[7]  += x * wb.w;
            a1[8]  += x * wc.x; a1[9]  += x * wc.y; a1[10] += x * wc.z; a1[11] += x * wc.w;
            a1[12] += x * wd.x; a1[13] += x * wd.y; a1[14] += x * wd.z; a1[15] += x * wd.w;
        }
#pragma unroll
        for (int i = 0; i < 16; ++i)
            a1[i] = fmaxf(a1[i] + rb1s[hh * 16 + i], 0.0f);
        float h1[32];
#pragma unroll
        for (int i = 0; i < 16; ++i) {
            float o = __shfl_xor(a1[i], 1);
            h1[hh * 16 + i] = a1[i];
            h1[(1 - hh) * 16 + i] = o;
        }
        float a2[8];
#pragma unroll
        for (int i = 0; i < 8; ++i) a2[i] = 0.f;
#pragma unroll 4
        for (int k = 0; k < 32; ++k) {
            float x = h1[k];
            const float* wr = &rw2s[k * 16 + hh * 8];
            float4 wa = *(const float4*)(wr);
            float4 wb = *(const float4*)(wr + 4);
            a2[0] += x * wa.x; a2[1] += x * wa.y; a2[2] += x * wa.z; a2[3] += x * wa.w;
            a2[4] += x * wb.x; a2[5] += x * wb.y; a2[6] += x * wb.z; a2[7] += x * wb.w;
        }
#pragma unroll
        for (int i = 0; i < 8; ++i)
            a2[i] = fmaxf(a2[i] + rb2s[hh * 8 + i], 0.0f);
        float h2[16];
#pragma unroll
        for (int i = 0; i < 8; ++i) {
            float o = __shfl_xor(a2[i], 1);
            h2[hh * 8 + i] = a2[i];
            h2[(1 - hh) * 8 + i] = o;
        }
        float a3 = rb3[0];
#pragma unroll
        for (int k = 0; k < 16; ++k) a3 += h2[k] * rw3s[k];
        float occ = softplusf_(a3);
        float dcon = occ * frcp(cap[ltp[(p0 + m) * TT + t]]);
        float s = dcon;
        s += __shfl_xor(s, 2);
        s += __shfl_xor(s, 4);
        s += __shfl_xor(s, 8);
        if ((tid & 15) == 0) out[p0 + m] = s;
    }
}

// ---------------------------------------------------------------------------
// K6: merged link+device GRU update. Template Kg => fully unrolled gathers.
// ---------------------------------------------------------------------------
template <int Kg>
__device__ __forceinline__ void edge_body(
    const unsigned short* __restrict__ wxT, const unsigned short* __restrict__ whT,
    const float* __restrict__ bx, const float* __restrict__ bh,
    const int* __restrict__ p2e, const unsigned short* __restrict__ pssb,
    float* __restrict__ state, int blk)
{
    __shared__ int idxs[16 * Kg * 2];
    __shared__ __align__(16) unsigned short Ab[16][72];
    __shared__ __align__(16) unsigned short Hbs[16][72];
    __shared__ __align__(16) float Hf[16][68];
    int tid = threadIdx.x;
    int r0 = blk * 16;
    for (int i = tid; i < 16 * Kg * 2; i += 256)
        idxs[i] = p2e[(size_t)r0 * Kg * 2 + i];
    __syncthreads();
    {
        int r = tid >> 4, c4 = (tid & 15) * 4;
        int row = r0 + r;
        float4 s = {0.f, 0.f, 0.f, 0.f};
#pragma unroll
        for (int k = 0; k < Kg; ++k) {
            int pi = idxs[(r * Kg + k) * 2];
            int ti = idxs[(r * Kg + k) * 2 + 1];
            ushort4 v = *(const ushort4*)(pssb + ((size_t)pi * TT + ti - 1) * 64 + c4);
            s.x += bf2f(v.x); s.y += bf2f(v.y);
            s.z += bf2f(v.z); s.w += bf2f(v.w);
        }
        uint2 ua;
        ua.x = pk2bf(s.x, s.y); ua.y = pk2bf(s.z, s.w);
        *(uint2*)&Ab[r][c4] = ua;
        float4 hv = *(const float4*)(state + (size_t)row * 64 + c4);
        *(float4*)&Hf[r][c4] = hv;
        uint2 uh;
        uh.x = pk2bf(hv.x, hv.y); uh.y = pk2bf(hv.z, hv.w);
        *(uint2*)&Hbs[r][c4] = uh;
    }
    __syncthreads();
    int lane = tid & 63, w = tid >> 6;
    int c = lane & 15, q = lane >> 4;
    int d = 16 * w + c;
    short8b fx[3][2], fh[3][2];
#pragma unroll
    for (int g = 0; g < 3; ++g)
#pragma unroll
        for (int kt = 0; kt < 2; ++kt) {
            int off = (g * 64 + 16 * w + c) * 64 + kt * 32 + q * 8;
            fx[g][kt] = *(const short8b*)(wxT + off);
            fh[g][kt] = *(const short8b*)(whT + off);
        }
    float bz = bx[d] + bh[d];
    float br = bx[64 + d] + bh[64 + d];
    float bxc = bx[128 + d];
    float bhc = bh[128 + d];
    f32x4 ax[3], ah[3];
    ax[0] = (f32x4){bz, bz, bz, bz};
    ax[1] = (f32x4){br, br, br, br};
    ax[2] = (f32x4){bxc, bxc, bxc, bxc};
    ah[0] = (f32x4){0.f, 0.f, 0.f, 0.f};
    ah[1] = (f32x4){0.f, 0.f, 0.f, 0.f};
    ah[2] = (f32x4){bhc, bhc, bhc, bhc};
#pragma unroll
    for (int kt = 0; kt < 2; ++kt) {
        short8b aA = *(const short8b*)&Ab[c][kt * 32 + q * 8];
        short8b aH = *(const short8b*)&Hbs[c][kt * 32 + q * 8];
#pragma unroll
        for (int g = 0; g < 3; ++g) {
            ax[g] = __builtin_amdgcn_mfma_f32_16x16x32_bf16(aA, fx[g][kt], ax[g], 0, 0, 0);
            ah[g] = __builtin_amdgcn_mfma_f32_16x16x32_bf16(aH, fh[g][kt], ah[g], 0, 0, 0);
        }
    }
#pragma unroll
    for (int r = 0; r < 4; ++r) {
        int m = q * 4 + r;
        float z  = sigmoidf_(ax[0][r] + ah[0][r]);
        float rr = sigmoidf_(ax[1][r] + ah[1][r]);
        float cc = tanhf_(ax[2][r] + rr * ah[2][r]);
        float hn = cc + z * (Hf[m][d] - cc);
        state[(size_t)(r0 + m) * 64 + d] = hn;
    }
}

__global__ __launch_bounds__(256) void k_edge_merged(
    const unsigned short* __restrict__ lwxT, const unsigned short* __restrict__ lwhT,
    const float* __restrict__ lbx, const float* __restrict__ lbh,
    const int* __restrict__ ptl,
    const unsigned short* __restrict__ dwxT, const unsigned short* __restrict__ dwhT,
    const float* __restrict__ dbx, const float* __restrict__ dbh,
    const int* __restrict__ ptn,
    const unsigned short* __restrict__ pssb,
    float* __restrict__ link_state, float* __restrict__ device_state)
{
    int b = blockIdx.x;
    if (b < LN / 16) {
        edge_body<KG>(lwxT, lwhT, lbx, lbh, ptl, pssb, link_state, b);
    } else {
        edge_body<K2G>(dwxT, dwhT, dbx, dbh, ptn, pssb, device_state, b - LN / 16);
    }
}

// ---------------------------------------------------------------------------
extern "C" void kernel_launch(void* const* d_in, const int* in_sizes, int n_in,
                              void* d_out, int out_size, void* d_ws, size_t ws_size,
                              hipStream_t stream) {
    const float* ft   = (const float*)d_in[0];
    const float* fpk  = (const float*)d_in[1];
    const float* fps  = (const float*)d_in[2];
    const float* cap  = (const float*)d_in[3];
    const float* pe_w1 = (const float*)d_in[4];
    const float* pe_b1 = (const float*)d_in[5];
    const float* pe_w2 = (const float*)d_in[6];
    const float* pe_b2 = (const float*)d_in[7];
    const float* le_w1 = (const float*)d_in[8];
    const float* le_b1 = (const float*)d_in[9];
    const float* le_w2 = (const float*)d_in[10];
    const float* le_b2 = (const float*)d_in[11];
    const float* de_w1 = (const float*)d_in[12];
    const float* de_b1 = (const float*)d_in[13];
    const float* de_w2 = (const float*)d_in[14];
    const float* de_b2 = (const float*)d_in[15];
    const float* pgru_wx = (const float*)d_in[16];
    const float* pgru_wh = (const float*)d_in[17];
    const float* pgru_bx = (const float*)d_in[18];
    const float* pgru_bh = (const float*)d_in[19];
    const float* lgru_wx = (const float*)d_in[20];
    const float* lgru_wh = (const float*)d_in[21];
    const float* lgru_bx = (const float*)d_in[22];
    const float* lgru_bh = (const float*)d_in[23];
    const float* dgru_wx = (const float*)d_in[24];
    const float* dgru_wh = (const float*)d_in[25];
    const float* dgru_bx = (const float*)d_in[26];
    const float* dgru_bh = (const float*)d_in[27];
    const float* ro_w1 = (const float*)d_in[28];
    const float* ro_b1 = (const float*)d_in[29];
    const float* ro_w2 = (const float*)d_in[30];
    const float* ro_b2 = (const float*)d_in[31];
    const float* ro_w3 = (const float*)d_in[32];
    const float* ro_b3 = (const float*)d_in[33];
    const int* ltp   = (const int*)d_in[34];
    const int* ntp   = (const int*)d_in[35];
    const int* ptl   = (const int*)d_in[36];
    const int* ptn   = (const int*)d_in[37];
    const int* ltn   = (const int*)d_in[38];
    const int* nodes = (const int*)d_in[39];
    const int* ldt   = (const int*)d_in[40];
    float* out = (float*)d_out;

    char* ws = (char*)d_ws;
    float* path_state = (float*)ws;      ws += (size_t)PN * 64 * 4;
    float* link_state = (float*)ws;      ws += (size_t)LN * 64 * 4;
    float* device_state = (float*)ws;    ws += (size_t)NN * 64 * 4;
    unsigned short* pssb = (unsigned short*)ws; ws += (size_t)PN * TT * 64 * 2;
    unsigned short* pwxT = (unsigned short*)ws; ws += 192 * 64 * 2;
    unsigned short* pwhT = (unsigned short*)ws; ws += 192 * 64 * 2;
    unsigned short* lwxT = (unsigned short*)ws; ws += 192 * 64 * 2;
    unsigned short* lwhT = (unsigned short*)ws; ws += 192 * 64 * 2;
    unsigned short* dwxT = (unsigned short*)ws; ws += 192 * 64 * 2;
    unsigned short* dwhT = (unsigned short*)ws; ws += 192 * 64 * 2;

    k_setup<<<1568, 256, 0, stream>>>(ft, fpk, fps, cap, ptl, ldt,
                                      pe_w1, pe_b1, pe_w2, pe_b2,
                                      le_w1, le_b1, le_w2, le_b2,
                                      pgru_wx, pgru_wh, lgru_wx, lgru_wh,
                                      dgru_wx, dgru_wh,
                                      pwxT, pwhT, lwxT, lwhT, dwxT, dwhT,
                                      path_state, link_state);
    k_device_encode<<<NN / 4, 256, 0, stream>>>(link_state, ltn, nodes, de_w1,
                                                de_b1, de_w2, de_b2, device_state);
    for (int it = 0; it < ITER - 1; ++it) {
        k_pscan<false><<<PN / 16, 256, 0, stream>>>(
            link_state, device_state, ltp, ntp, pwxT, pwhT, pgru_bx, pgru_bh,
            path_state, pssb, ro_w1, ro_b1, ro_w2, ro_b2, ro_w3, ro_b3, cap, out);
        k_edge_merged<<<LN / 16 + NN / 16, 256, 0, stream>>>(
            lwxT, lwhT, lgru_bx, lgru_bh, ptl,
            dwxT, dwhT, dgru_bx, dgru_bh, ptn,
            pssb, link_state, device_state);
    }
    // final iteration: pscan + fused readout (edge update after it is dead work)
    k_pscan<true><<<PN / 16, 256, 0, stream>>>(
        link_state, device_state, ltp, ntp, pwxT, pwhT, pgru_bx, pgru_bh,
        path_state, pssb, ro_w1, ro_b1, ro_w2, ro_b2, ro_w3, ro_b3, cap, out);
}